// Round 13
// baseline (221.146 us; speedup 1.0000x reference)
//
#include <hip/hip_runtime.h>
#include <hip/hip_bf16.h>
#include <cstdint>
#include <cstddef>

typedef __attribute__((ext_vector_type(8))) _Float16 half8;
typedef __attribute__((ext_vector_type(4))) float f32x4;
typedef __attribute__((ext_vector_type(8))) unsigned short ushort8v;
typedef __attribute__((ext_vector_type(4))) unsigned short ushort4v;

__device__ __forceinline__ unsigned short f2h_bits(float x) {
  _Float16 h = (_Float16)x;
  union { _Float16 h; unsigned short u; } cv; cv.h = h; return cv.u;
}

__device__ __forceinline__ void barrier_raw() {
  asm volatile("" ::: "memory");
  __builtin_amdgcn_s_barrier();
  asm volatile("" ::: "memory");
}
template<int N> __device__ __forceinline__ void vmw() {
  static_assert(N == 0 || N == 3 || N == 4 || N == 6, "unsupported vmcnt");
  if constexpr (N == 0) asm volatile("s_waitcnt vmcnt(0)" ::: "memory");
  if constexpr (N == 3) asm volatile("s_waitcnt vmcnt(3)" ::: "memory");
  if constexpr (N == 4) asm volatile("s_waitcnt vmcnt(4)" ::: "memory");
  if constexpr (N == 6) asm volatile("s_waitcnt vmcnt(6)" ::: "memory");
}
__device__ __forceinline__ void lgkm0() {
  asm volatile("s_waitcnt lgkmcnt(0)" ::: "memory");
}

// pinned 16B global load: compiler cannot sink/merge it; WE own the waitcnt.
__device__ __forceinline__ half8 gload16(const unsigned short* p) {
  half8 r;
  asm volatile("global_load_dwordx4 %0, %1, off" : "=v"(r) : "v"(p));
  return r;
}

// ---------------- prep kernels ----------------

__global__ __launch_bounds__(256) void k_transpose_f16(const float* __restrict__ W,
                                                       unsigned short* __restrict__ Wt,
                                                       int Kd, int N) {
  int tid = blockIdx.x * 256 + threadIdx.x;
  int total = (Kd >> 3) * N;
  if (tid >= total) return;
  int kc = tid / N;
  int n  = tid - kc * N;
  int k0 = kc << 3;
  ushort8v o;
#pragma unroll
  for (int j = 0; j < 8; ++j) o[j] = f2h_bits(W[(size_t)(k0 + j) * N + n]);
  *(ushort8v*)(&Wt[(size_t)n * Kd + k0]) = o;
}

// Build unpacked head weight whd [2304][512] fp16 and bias bhd [2304] f32.
// rows 0..127: mu; 128..2175: tril unpacked (k*256+i*16+j, zero if j>i);
// 2176..2183: pi; 2184..2303: zero pad.  (R6-verified)
__global__ __launch_bounds__(256) void k_build_head(
    const float* __restrict__ Wmu, const float* __restrict__ Wt,
    const float* __restrict__ Wpi,
    const float* __restrict__ bmu, const float* __restrict__ bt,
    const float* __restrict__ bpi,
    unsigned short* __restrict__ whd, float* __restrict__ bhd)
{
  int tid = blockIdx.x * 256 + threadIdx.x;
  if (tid >= 2304 * 64) return;
  int r  = tid >> 6;
  int d0 = (tid & 63) << 3;

  const float* src = nullptr; int stride = 0;
  if (r < 128) { src = Wmu + r; stride = 128; }
  else if (r < 2176) {
    int rU = r - 128, k = rU >> 8, i = (rU >> 4) & 15, j = rU & 15;
    if (j <= i) { src = Wt + k * 136 + ((i * (i + 1)) >> 1) + j; stride = 1088; }
  } else if (r < 2184) { src = Wpi + (r - 2176); stride = 8; }

  ushort8v o;
#pragma unroll
  for (int jj = 0; jj < 8; ++jj)
    o[jj] = src ? f2h_bits(src[(size_t)(d0 + jj) * stride]) : (unsigned short)0;
  *(ushort8v*)(&whd[(size_t)r * 512 + d0]) = o;

  if (d0 == 0) {
    float b = 0.f;
    if (r < 128) b = bmu[r];
    else if (r < 2176) {
      int rU = r - 128, k = rU >> 8, i = (rU >> 4) & 15, j = rU & 15;
      if (j <= i) b = bt[k * 136 + ((i * (i + 1)) >> 1) + j];
    } else if (r < 2184) b = bpi[r - 2176];
    bhd[r] = b;
  }
}

// ---- shared epilogue helpers (swapped-operand layout: row=l15-side, col=lk*4+reg) ----

__device__ __forceinline__ void epi_relu_h(const f32x4& a, const float* bias, int col0,
                                           unsigned short* Hout, size_t row, int N) {
  float4 b4 = *(const float4*)&bias[col0];
  ushort4v o;
  float v0 = a[0] + b4.x; o[0] = f2h_bits(v0 > 0.f ? v0 : 0.f);
  float v1 = a[1] + b4.y; o[1] = f2h_bits(v1 > 0.f ? v1 : 0.f);
  float v2 = a[2] + b4.z; o[2] = f2h_bits(v2 > 0.f ? v2 : 0.f);
  float v3 = a[3] + b4.w; o[3] = f2h_bits(v3 > 0.f ? v3 : 0.f);
  *(ushort4v*)&Hout[row * N + col0] = o;
}

// head epilogue, N=2304 layout (R6-verified)
__device__ __forceinline__ void epi_head(const f32x4& a, const float* bias, int col0,
                                         size_t row, float* out_pi, float* out_mu,
                                         float* out_tril) {
  if (col0 >= 2184) return;   // pad
  float4 b4 = *(const float4*)&bias[col0];
  float v[4] = { a[0] + b4.x, a[1] + b4.y, a[2] + b4.z, a[3] + b4.w };
  if (col0 < 128) {
    *(float4*)&out_mu[row * 128 + col0] = make_float4(v[0], v[1], v[2], v[3]);
  } else if (col0 < 2176) {
    const int cc0 = col0 - 128;
    const int i   = (cc0 >> 4) & 15;
    const int j0  = cc0 & 15;
#pragma unroll
    for (int r = 0; r < 4; ++r) if (j0 + r == i) v[r] = expf(v[r]);
    *(float4*)&out_tril[row * 2048 + cc0] = make_float4(v[0], v[1], v[2], v[3]);
  } else {
    // pi: lanes lk=0 hold cols 2176-79, lk=1 hold 2180-83 for the same row (lane^16)
    float m4 = fmaxf(fmaxf(v[0], v[1]), fmaxf(v[2], v[3]));
    float mx = fmaxf(m4, __shfl_xor(m4, 16));
    float e[4], s4 = 0.f;
#pragma unroll
    for (int r = 0; r < 4; ++r) { e[r] = expf(v[r] - mx); s4 += e[r]; }
    float sm = s4 + __shfl_xor(s4, 16);
    *(float4*)&out_pi[row * 8 + (col0 - 2176)] =
        make_float4(e[0] / sm, e[1] / sm, e[2] / sm, e[3] / sm);
  }
}

// -------- head: A from GLOBAL->REG (halves LDS-read pipe load), B in 3-buf LDS --------
// Rationale (m134 arithmetic): old kernel's 8 ds_read_b128/thread/step saturated the
// LDS pipe (~86%); A-frags are 16B contiguous in h2 -> load straight to registers.
// vmcnt ledger: prologue issues B0,B1,A0 -> vmw<4> (forces B0,B1 per-wave) + barrier.
// Steady step t: issue stageB(t+2):2, A(t+1):4 -> vmw<6> (allow those 6; forces A(t),
// B(t+1)); compute(t); barrier (protects buf (t+3)%3 overwrite next step).
// Tail: t=14 vmw<4>, t=15 vmw<0>. Cross-wave B(t) visibility: every wave's vmw at
// step t-1 forces its own stageB(t) chunks before the shared end-of-step barrier.

__global__ __launch_bounds__(256, 4) void k_head_areg(
    const unsigned short* __restrict__ A,    // h2 [16384][512] f16
    const unsigned short* __restrict__ Bt,   // whd [2304][512] f16
    const float* __restrict__ bias,
    float* __restrict__ out_pi,
    float* __restrict__ out_mu,
    float* __restrict__ out_tril)
{
  constexpr int Kd = 512, nNb = 18;
  __shared__ unsigned short Bld[3][128 * 32];

  const int tid  = threadIdx.x;
  const int lane = tid & 63;
  const int wv   = tid >> 6;
  const int wr   = wv >> 1;
  const int wc   = wv & 1;
  const int l15  = lane & 15;
  const int lk   = lane >> 4;

  const int cpx = gridDim.x >> 3;
  const int bid = blockIdx.x;
  const int swz = (bid & 7) * cpx + (bid >> 3);
  const int bm  = (swz / nNb) << 7;
  const int bn  = (swz % nNb) << 7;

  f32x4 acc[4][4] = {};

  // A-frag base pointers: h2[bm + wr*64 + m*16 + l15][lk*8]  (16B contiguous per lane)
  const unsigned short* a0p = A + (size_t)(bm + (wr << 6) + 0  + l15) * Kd + (lk << 3);
  const unsigned short* a1p = a0p + (size_t)16 * Kd;
  const unsigned short* a2p = a0p + (size_t)32 * Kd;
  const unsigned short* a3p = a0p + (size_t)48 * Kd;

  const unsigned short* bBase = Bt + (size_t)bn * Kd;
  const int xo   = ((lk ^ ((l15 >> 1) & 3)) << 3);
  const int colB = (wc << 6) + l15;

  auto stageB = [&](int bb, int kt) {
    const int k0 = kt << 5;
#pragma unroll
    for (int i = 0; i < 2; ++i) {
      const int c_  = (wv << 6) + (i << 8) + lane;   // 512 chunks of 16B
      const int row = c_ >> 2;
      const int sc  = (((c_ & 3) ^ ((c_ >> 3) & 3)) << 3);
      __builtin_amdgcn_global_load_lds(
          (const __attribute__((address_space(1))) void*)(bBase + (size_t)row * Kd + k0 + sc),
          (__attribute__((address_space(3))) void*)(&Bld[bb][((wv << 6) + (i << 8)) << 3]),
          16, 0, 0);
    }
  };

  half8 aE0, aE1, aE2, aE3, aO0, aO1, aO2, aO3;

#define AISSUE(S, t) do {                 \
    a##S##0 = gload16(a0p + (t) * 32);    \
    a##S##1 = gload16(a1p + (t) * 32);    \
    a##S##2 = gload16(a2p + (t) * 32);    \
    a##S##3 = gload16(a3p + (t) * 32);    \
  } while (0)

#define HCOMP(S, b) do {                                                                   \
    half8 bf0 = *(const half8*)&Bld[b][(size_t)(colB + 0)  * 32 + xo];                     \
    half8 bf1 = *(const half8*)&Bld[b][(size_t)(colB + 16) * 32 + xo];                     \
    half8 bf2 = *(const half8*)&Bld[b][(size_t)(colB + 32) * 32 + xo];                     \
    half8 bf3 = *(const half8*)&Bld[b][(size_t)(colB + 48) * 32 + xo];                     \
    __builtin_amdgcn_s_setprio(1);                                                        \
    acc[0][0] = __builtin_amdgcn_mfma_f32_16x16x32_f16(bf0, a##S##0, acc[0][0], 0, 0, 0); \
    acc[0][1] = __builtin_amdgcn_mfma_f32_16x16x32_f16(bf1, a##S##0, acc[0][1], 0, 0, 0); \
    acc[0][2] = __builtin_amdgcn_mfma_f32_16x16x32_f16(bf2, a##S##0, acc[0][2], 0, 0, 0); \
    acc[0][3] = __builtin_amdgcn_mfma_f32_16x16x32_f16(bf3, a##S##0, acc[0][3], 0, 0, 0); \
    acc[1][0] = __builtin_amdgcn_mfma_f32_16x16x32_f16(bf0, a##S##1, acc[1][0], 0, 0, 0); \
    acc[1][1] = __builtin_amdgcn_mfma_f32_16x16x32_f16(bf1, a##S##1, acc[1][1], 0, 0, 0); \
    acc[1][2] = __builtin_amdgcn_mfma_f32_16x16x32_f16(bf2, a##S##1, acc[1][2], 0, 0, 0); \
    acc[1][3] = __builtin_amdgcn_mfma_f32_16x16x32_f16(bf3, a##S##1, acc[1][3], 0, 0, 0); \
    acc[2][0] = __builtin_amdgcn_mfma_f32_16x16x32_f16(bf0, a##S##2, acc[2][0], 0, 0, 0); \
    acc[2][1] = __builtin_amdgcn_mfma_f32_16x16x32_f16(bf1, a##S##2, acc[2][1], 0, 0, 0); \
    acc[2][2] = __builtin_amdgcn_mfma_f32_16x16x32_f16(bf2, a##S##2, acc[2][2], 0, 0, 0); \
    acc[2][3] = __builtin_amdgcn_mfma_f32_16x16x32_f16(bf3, a##S##2, acc[2][3], 0, 0, 0); \
    acc[3][0] = __builtin_amdgcn_mfma_f32_16x16x32_f16(bf0, a##S##3, acc[3][0], 0, 0, 0); \
    acc[3][1] = __builtin_amdgcn_mfma_f32_16x16x32_f16(bf1, a##S##3, acc[3][1], 0, 0, 0); \
    acc[3][2] = __builtin_amdgcn_mfma_f32_16x16x32_f16(bf2, a##S##3, acc[3][2], 0, 0, 0); \
    acc[3][3] = __builtin_amdgcn_mfma_f32_16x16x32_f16(bf3, a##S##3, acc[3][3], 0, 0, 0); \
    __builtin_amdgcn_s_setprio(0);                                                        \
    __builtin_amdgcn_sched_barrier(0);                                                    \
  } while (0)

#define SB __builtin_amdgcn_sched_barrier(0)
  // prologue
  stageB(0, 0); stageB(1, 1);
  AISSUE(E, 0);
  vmw<4>(); SB;            // forces B0,B1 (per-wave) before the common barrier
  barrier_raw();

  // steady steps t=0..13 (A(t) in set t&1; B(t) in buf t%3)
  stageB(2, 2);  AISSUE(O, 1);  vmw<6>(); SB; HCOMP(E, 0); barrier_raw();   // t=0
  stageB(0, 3);  AISSUE(E, 2);  vmw<6>(); SB; HCOMP(O, 1); barrier_raw();   // t=1
  stageB(1, 4);  AISSUE(O, 3);  vmw<6>(); SB; HCOMP(E, 2); barrier_raw();   // t=2
  stageB(2, 5);  AISSUE(E, 4);  vmw<6>(); SB; HCOMP(O, 0); barrier_raw();   // t=3
  stageB(0, 6);  AISSUE(O, 5);  vmw<6>(); SB; HCOMP(E, 1); barrier_raw();   // t=4
  stageB(1, 7);  AISSUE(E, 6);  vmw<6>(); SB; HCOMP(O, 2); barrier_raw();   // t=5
  stageB(2, 8);  AISSUE(O, 7);  vmw<6>(); SB; HCOMP(E, 0); barrier_raw();   // t=6
  stageB(0, 9);  AISSUE(E, 8);  vmw<6>(); SB; HCOMP(O, 1); barrier_raw();   // t=7
  stageB(1, 10); AISSUE(O, 9);  vmw<6>(); SB; HCOMP(E, 2); barrier_raw();   // t=8
  stageB(2, 11); AISSUE(E, 10); vmw<6>(); SB; HCOMP(O, 0); barrier_raw();   // t=9
  stageB(0, 12); AISSUE(O, 11); vmw<6>(); SB; HCOMP(E, 1); barrier_raw();   // t=10
  stageB(1, 13); AISSUE(E, 12); vmw<6>(); SB; HCOMP(O, 2); barrier_raw();   // t=11
  stageB(2, 14); AISSUE(O, 13); vmw<6>(); SB; HCOMP(E, 0); barrier_raw();   // t=12
  stageB(0, 15); AISSUE(E, 14); vmw<6>(); SB; HCOMP(O, 1); barrier_raw();   // t=13
  // tails
  AISSUE(O, 15); vmw<4>(); SB; HCOMP(E, 2); barrier_raw();                  // t=14
  vmw<0>(); SB; HCOMP(O, 0);                                                // t=15
#undef AISSUE
#undef HCOMP
#undef SB

  // epilogue: row = bm + wr*64 + m*16 + l15 ; col0 = bn + wc*64 + n*16 + lk*4
#pragma unroll
  for (int m = 0; m < 4; ++m) {
    const size_t row = bm + (wr << 6) + (m << 4) + l15;
#pragma unroll
    for (int n = 0; n < 4; ++n) {
      const int col0 = bn + (wc << 6) + (n << 4) + (lk << 2);
      epi_head(acc[m][n], bias, col0, row, out_pi, out_mu, out_tril);
    }
  }
}

// -------- L0: fused f32->f16 GEMM, 128x128, 2-buffer, T14-split A-staging (R12) --------

__global__ __launch_bounds__(256) void k_gemm_l0(
    const float* __restrict__ X,
    const unsigned short* __restrict__ Bt,   // [1024][256] f16
    const float* __restrict__ bias,
    unsigned short* __restrict__ Hout)       // h0 [16384][1024] f16
{
  constexpr int Kd = 256, N = 1024, nNb = 8;
  __shared__ unsigned short Alds[2][128 * 32];
  __shared__ unsigned short Blds[2][128 * 32];

  const int tid  = threadIdx.x;
  const int lane = tid & 63;
  const int wv   = tid >> 6;
  const int wr   = wv >> 1;
  const int wc   = wv & 1;
  const int l15  = lane & 15;
  const int lk   = lane >> 4;

  const int cpx = gridDim.x >> 3;
  const int bid = blockIdx.x;
  const int swz = (bid & 7) * cpx + (bid >> 3);
  const int bm  = (swz / nNb) << 7;
  const int bn  = (swz % nNb) << 7;

  f32x4 acc[4][4] = {};

  const float*          aBase = X  + (size_t)bm * Kd;
  const unsigned short* bBase = Bt + (size_t)bn * Kd;

  const int xo = ((lk ^ ((l15 >> 1) & 3)) << 3);

  const int c0   = (wv << 6) + lane;
  const int c1   = c0 + 256;
  const int row0 = c0 >> 2, row1 = c1 >> 2;
  const int sc0  = (((c0 & 3) ^ ((c0 >> 3) & 3)) << 3);
  const int sc1  = (((c1 & 3) ^ ((c1 >> 3) & 3)) << 3);

  auto issueB = [&](int bb, int kt) {
    const int k0 = kt << 5;
#pragma unroll
    for (int i = 0; i < 2; ++i) {
      const int cbase = (wv << 6) + (i << 8);
      const int c_    = cbase + lane;
      const int row   = c_ >> 2;
      const int sc    = (((c_ & 3) ^ ((c_ >> 3) & 3)) << 3);
      __builtin_amdgcn_global_load_lds(
          (const __attribute__((address_space(1))) void*)(bBase + (size_t)row * Kd + k0 + sc),
          (__attribute__((address_space(3))) void*)(&Blds[bb][cbase << 3]),
          16, 0, 0);
    }
  };

  float4 p0, p1, p2, p3;
  auto loadA = [&](int kt) {
    const int k0 = kt << 5;
    const float* s0 = aBase + (size_t)row0 * Kd + k0 + sc0;
    const float* s1 = aBase + (size_t)row1 * Kd + k0 + sc1;
    p0 = *(const float4*)(s0);
    p1 = *(const float4*)(s0 + 4);
    p2 = *(const float4*)(s1);
    p3 = *(const float4*)(s1 + 4);
  };
  auto writeA = [&](int bb) {
    half8 h0, h1;
    h0[0]=(_Float16)p0.x; h0[1]=(_Float16)p0.y; h0[2]=(_Float16)p0.z; h0[3]=(_Float16)p0.w;
    h0[4]=(_Float16)p1.x; h0[5]=(_Float16)p1.y; h0[6]=(_Float16)p1.z; h0[7]=(_Float16)p1.w;
    h1[0]=(_Float16)p2.x; h1[1]=(_Float16)p2.y; h1[2]=(_Float16)p2.z; h1[3]=(_Float16)p2.w;
    h1[4]=(_Float16)p3.x; h1[5]=(_Float16)p3.y; h1[6]=(_Float16)p3.z; h1[7]=(_Float16)p3.w;
    *(half8*)&Alds[bb][c0 << 3] = h0;
    *(half8*)&Alds[bb][c1 << 3] = h1;
  };

  const int nk = Kd >> 5;   // 8
  loadA(0); issueB(0, 0); writeA(0);
  __syncthreads();

  int cur = 0;
  for (int kt = 0; kt < nk; ++kt) {
    const bool pre = (kt + 1 < nk);
    if (pre) { loadA(kt + 1); issueB(cur ^ 1, kt + 1); }

    half8 af[4], bfr[4];
#pragma unroll
    for (int m = 0; m < 4; ++m)
      af[m]  = *(const half8*)&Alds[cur][((wr << 6) + (m << 4) + l15) * 32 + xo];
#pragma unroll
    for (int n = 0; n < 4; ++n)
      bfr[n] = *(const half8*)&Blds[cur][((wc << 6) + (n << 4) + l15) * 32 + xo];

    __builtin_amdgcn_s_setprio(1);
#pragma unroll
    for (int m = 0; m < 4; ++m)
#pragma unroll
      for (int n = 0; n < 4; ++n)
        acc[m][n] = __builtin_amdgcn_mfma_f32_16x16x32_f16(bfr[n], af[m], acc[m][n], 0, 0, 0);
    __builtin_amdgcn_s_setprio(0);

    if (pre) writeA(cur ^ 1);
    __syncthreads();
    cur ^= 1;
  }

#pragma unroll
  for (int m = 0; m < 4; ++m) {
    const size_t row = bm + (wr << 6) + (m << 4) + l15;
#pragma unroll
    for (int n = 0; n < 4; ++n) {
      const int col0 = bn + (wc << 6) + (n << 4) + (lk << 2);
      epi_relu_h(acc[m][n], bias, col0, Hout, row, N);
    }
  }
}

// -------- 8-phase counted-vmcnt GEMM (rounds 4-12 verified) — L1/L2 --------

template<int NH, int M_rep>
__device__ __forceinline__ void mfma_phase(const half8* af, const half8* bf,
                                           f32x4 (*acc)[4]) {
  __builtin_amdgcn_s_setprio(1);
#pragma unroll
  for (int m = 0; m < M_rep; ++m) {
    acc[m][NH * 2 + 0] = __builtin_amdgcn_mfma_f32_16x16x32_f16(bf[0], af[m], acc[m][NH * 2 + 0], 0, 0, 0);
    acc[m][NH * 2 + 1] = __builtin_amdgcn_mfma_f32_16x16x32_f16(bf[1], af[m], acc[m][NH * 2 + 1], 0, 0, 0);
  }
  __builtin_amdgcn_s_setprio(0);
}

template<int BM, int BN>
__global__ __launch_bounds__(512) void k_gemm8p(
    const unsigned short* __restrict__ A,
    const unsigned short* __restrict__ Bt,
    int Kd, int N, int nNb,
    const float* __restrict__ bias,
    unsigned short* __restrict__ Hout)
{
  constexpr int M_rep = BM / 32;
  constexpr int A_LD  = BM / 128;
  constexpr int B_LD  = BN / 128;
  constexpr int WN    = A_LD + B_LD;

  __shared__ unsigned short Ald[2][2][BM * 32];
  __shared__ unsigned short Bld[2][2][BN * 32];

  const int tid  = threadIdx.x;
  const int lane = tid & 63;
  const int wid  = tid >> 6;
  const int wm   = wid >> 2;
  const int wn   = wid & 3;
  const int l15  = lane & 15;
  const int lk   = lane >> 4;

  const int cpx = gridDim.x >> 3;
  const int bid = blockIdx.x;
  const int swz = (bid & 7) * cpx + (bid >> 3);
  const int bm  = (swz / nNb) * BM;
  const int bn  = (swz % nNb) * BN;

  const unsigned short* aBase = A  + (size_t)bm * Kd;
  const unsigned short* bBase = Bt + (size_t)bn * Kd;

  f32x4 acc[M_rep][4] = {};

  const int xo   = ((lk ^ ((l15 >> 1) & 3)) << 3);
  const int rowA = wm * (BM / 2) + l15;
  const int colB = wn * 64 + l15;

  auto stageA = [&](int bb, int h, int k0) {
#pragma unroll
    for (int i = 0; i < A_LD; ++i) {
      const int cbase = (wid << 6) + (i << 9);
      const int c_    = cbase + lane;
      const int row   = c_ >> 2;
      const int sc    = (((c_ & 3) ^ ((c_ >> 3) & 3)) << 3);
      __builtin_amdgcn_global_load_lds(
          (const __attribute__((address_space(1))) void*)(aBase + (size_t)row * Kd + k0 + h * 32 + sc),
          (__attribute__((address_space(3))) void*)(&Ald[bb][h][(size_t)cbase << 3]),
          16, 0, 0);
    }
  };
  auto stageB = [&](int bb, int h, int k0) {
#pragma unroll
    for (int i = 0; i < B_LD; ++i) {
      const int cbase = (wid << 6) + (i << 9);
      const int c_    = cbase + lane;
      const int row   = c_ >> 2;
      const int sc    = (((c_ & 3) ^ ((c_ >> 3) & 3)) << 3);
      __builtin_amdgcn_global_load_lds(
          (const __attribute__((address_space(1))) void*)(bBase + (size_t)row * Kd + k0 + h * 32 + sc),
          (__attribute__((address_space(3))) void*)(&Bld[bb][h][(size_t)cbase << 3]),
          16, 0, 0);
    }
  };

#define RD_A(kk)                                                                 \
  {                                                                              \
    _Pragma("unroll")                                                            \
    for (int m = 0; m < M_rep; ++m)                                              \
      af[m] = *(const half8*)&Ald[cur][kk][(size_t)(rowA + m * 16) * 32 + xo];   \
  }
#define RD_B(kk, nh)                                                             \
  {                                                                              \
    _Pragma("unroll")                                                            \
    for (int n2 = 0; n2 < 2; ++n2)                                               \
      bf[n2] = *(const half8*)&Bld[cur][kk][(size_t)(colB + ((nh) * 2 + n2) * 16) * 32 + xo]; \
  }

  const int nk = Kd >> 6;
  stageA(0, 0, 0); stageB(0, 0, 0); stageA(0, 1, 0); stageB(0, 1, 0);
  { if constexpr (WN == 3) vmw<3>(); else vmw<4>(); }
  barrier_raw();

  int cur = 0;
  for (int kt = 0; kt < nk; ++kt) {
    const bool pre = (kt + 1 < nk);
    const int  k0n = (kt + 1) << 6;
    half8 af[M_rep], bf[2];

    RD_A(0); RD_B(0, 0);
    if (pre) stageA(cur ^ 1, 0, k0n);
    barrier_raw(); lgkm0();
    mfma_phase<0, M_rep>(af, bf, acc);
    barrier_raw();

    RD_B(0, 1);
    if (pre) stageB(cur ^ 1, 0, k0n);
    barrier_raw(); lgkm0();
    mfma_phase<1, M_rep>(af, bf, acc);
    if (pre) { if constexpr (WN == 3) vmw<3>(); else vmw<4>(); } else vmw<0>();
    barrier_raw();

    RD_A(1); RD_B(1, 0);
    if (pre) stageA(cur ^ 1, 1, k0n);
    barrier_raw(); lgkm0();
    mfma_phase<0, M_rep>(af, bf, acc);
    barrier_raw();

    RD_B(1, 1);
    if (pre) stageB(cur ^ 1, 1, k0n);
    barrier_raw(); lgkm0();
    mfma_phase<1, M_rep>(af, bf, acc);
    if (pre) { if constexpr (WN == 3) vmw<3>(); else vmw<4>(); }
    barrier_raw();

    cur ^= 1;
  }
#undef RD_A
#undef RD_B

#pragma unroll
  for (int m = 0; m < M_rep; ++m) {
    const size_t row = bm + wm * (BM / 2) + (m << 4) + l15;
#pragma unroll
    for (int n = 0; n < 4; ++n) {
      const int col0 = bn + wn * 64 + (n << 4) + (lk << 2);
      epi_relu_h(acc[m][n], bias, col0, Hout, row, N);
    }
  }
}

// ---------------- launch ----------------

extern "C" void kernel_launch(void* const* d_in, const int* in_sizes, int n_in,
                              void* d_out, int out_size, void* d_ws, size_t ws_size,
                              hipStream_t stream)
{
  const float* x   = (const float*)d_in[0];
  const float* W0  = (const float*)d_in[1];
  const float* b0  = (const float*)d_in[2];
  const float* W1  = (const float*)d_in[3];
  const float* b1  = (const float*)d_in[4];
  const float* W2  = (const float*)d_in[5];
  const float* b2  = (const float*)d_in[6];
  const float* Wpi = (const float*)d_in[7];
  const float* bpi = (const float*)d_in[8];
  const float* Wmu = (const float*)d_in[9];
  const float* bmu = (const float*)d_in[10];
  const float* Wt  = (const float*)d_in[11];
  const float* bt  = (const float*)d_in[12];

  char* ws = (char*)d_ws;
  unsigned short* h0  = (unsigned short*)(ws + 8388608);   // 33,554,432 B
  unsigned short* h1  = (unsigned short*)(ws + 41943040);  // 33,554,432 B
  unsigned short* h2  = (unsigned short*)(ws + 8388608);   // 16,777,216 B (aliases h0 — dead by then)
  unsigned short* w0b = (unsigned short*)(ws + 75497472);  //    524,288 B [1024][256]
  unsigned short* w1b = (unsigned short*)(ws + 76021760);  //  2,097,152 B [1024][1024]
  unsigned short* w2b = (unsigned short*)(ws + 78118912);  //  1,048,576 B [512][1024]
  unsigned short* whd = (unsigned short*)(ws + 79167488);  //  2,359,296 B [2304][512]
  float*          bhd = (float*)         (ws + 81526784);  //      9,216 B [2304]

  float* out_pi   = (float*)d_out;                // 131072
  float* out_mu   = (float*)d_out + 131072;       // 2097152
  float* out_tril = (float*)d_out + 2228224;      // 33554432

  // prep
  k_transpose_f16<<<128, 256, 0, stream>>>(W0, w0b, 256, 1024);
  k_transpose_f16<<<512, 256, 0, stream>>>(W1, w1b, 1024, 1024);
  k_transpose_f16<<<256, 256, 0, stream>>>(W2, w2b, 1024, 512);
  k_build_head<<<576, 256, 0, stream>>>(Wmu, Wt, Wpi, bmu, bt, bpi, whd, bhd);

  // L0: reads x f32 directly, converts during staging (T14 split), 1024 blocks
  k_gemm_l0<<<1024, 256, 0, stream>>>(x, w0b, b0, h0);
  // L1/L2: K=1024 -> 256-class 8-phase, 256 blocks (1/CU exact)
  k_gemm8p<256, 256><<<256, 512, 0, stream>>>(h0, w1b, 1024, 1024, 4, b1, h1);
  k_gemm8p<128, 256><<<256, 512, 0, stream>>>(h1, w2b, 1024, 512, 2, b2, h2);
  // head: A global->reg (LDS pipe halved), B 3-buf LDS, counted vmcnt, 2304 blocks
  k_head_areg<<<2304, 256, 0, stream>>>(h2, whd, bhd, out_pi, out_mu, out_tril);
}